// Round 21
// baseline (418.730 us; speedup 1.0000x reference)
//
#include <hip/hip_runtime.h>

// SwinTransformerBlock3D on MI355X (gfx950). fp32 in/out, f16 MFMA internals.
//
// k_pm v2: ZERO-BARRIER dataflow. Weights (396 KB, L2-resident) are read as
// MFMA B-frags directly from global (16B contiguous per lane) -- no wb LDS
// tile, no register staging pipeline, no __syncthreads at all. LDS = hc only
// (17.4 KB). Diagnosis: 3 occupancy variants all hit 82-88 us because the
// 18-barrier x 9-staging serial chain dominates (~96% non-MFMA); this removes
// the chain entirely and lets waves overlap freely.
//
// ws layout (bytes):
//   [0)           qkv   f16 [256][343][384]   67,436,544
//   [67,436,544)  aout  f16 [256][343][128]   22,478,848
//   [89,915,392)  biasH f16 [4][22(rt)][22(nt)][16(ml)][4(quad)][4(reg)] 991,232
//   [91,897,856)  w1h   f16 [512][128]           131,072
//   [92,028,928)  w2h   f16 [128][512]           131,072
//   [92,160,000)  wqh   f16 [384][128]            98,304
//   [92,258,304)  wph   f16 [128][128]            32,768
//   total 92,291,072      (x1 lives in registers inside k_pm)

typedef __attribute__((ext_vector_type(8))) _Float16 half8;
typedef __attribute__((ext_vector_type(4))) _Float16 half4;
typedef __attribute__((ext_vector_type(4))) float floatx4;

#define DEV static __device__ __forceinline__

DEV floatx4 MFMA(half8 a, half8 b, floatx4 c) {
  return __builtin_amdgcn_mfma_f32_16x16x32_f16(a, b, c, 0, 0, 0);
}
DEV floatx4 MFMA16(half4 a, half4 b, floatx4 c) {
  return __builtin_amdgcn_mfma_f32_16x16x16f16(a, b, c, 0, 0, 0);
}

DEV float gelu_f(float v) {  // sigmoid-form GELU (abs err <~0.01; margin 0.109)
  return v / (1.f + __expf(-1.702f * v));
}

DEV void f4arr(float4 v, float o[4]) {
  o[0] = v.x; o[1] = v.y; o[2] = v.z; o[3] = v.w;
}

// ---- weight tile pipeline (k_ln_qkv only): [128 x 128] via registers ------
DEV void stage_load(half8 pf[8], const _Float16* src, int rst, int tid) {
#pragma unroll
  for (int it = 0; it < 8; ++it) {
    int e = it * 256 + tid;
    int row = e >> 4, seg = e & 15;
    pf[it] = *(const half8*)&src[(size_t)row * rst + seg * 8];
  }
}
DEV void stage_store(_Float16* wb, const half8 pf[8], int tid) {
#pragma unroll
  for (int it = 0; it < 8; ++it) {
    int e = it * 256 + tid;
    int row = e >> 4, seg = e & 15;
    *(half8*)&wb[row * 136 + seg * 8] = pf[it];
  }
}
DEV void stage_tile(_Float16* wb, const _Float16* src, int rst, int tid) {
  half8 pf[8];
  stage_load(pf, src, rst, tid);
  stage_store(wb, pf, tid);
}

// ---- combined prep: rel-bias into swapped-S D-layout (f16) + weights -------
// biasH layout [h][rt][nt][ml][quad][reg] (nt innermost tile dim -> 512 B
// stride, foldable into immediate offsets in k_attn's group loop).
__global__ __launch_bounds__(256) void k_prep(
    const float* __restrict__ rel, _Float16* __restrict__ biasH,
    const float* __restrict__ w1, const float* __restrict__ w2,
    const float* __restrict__ wq, const float* __restrict__ wp,
    _Float16* __restrict__ w1h, _Float16* __restrict__ w2h,
    _Float16* __restrict__ wqh, _Float16* __restrict__ wph) {
  int gid = blockIdx.x * 256 + threadIdx.x;
  if (gid < 495616) {  // biasH[h][rt][nt][ml][quad][reg]; pads = -30000
    int reg = gid & 3, quad = (gid >> 2) & 3, ml = (gid >> 4) & 15;
    int u = gid >> 8;
    int nt = u % 22; u /= 22;
    int rt = u % 22; int h = u / 22;
    int q = rt * 16 + ml, kv = nt * 16 + quad * 4 + reg;
    float val = -30000.f;
    if (q < 343 && kv < 343) {
      int lzi = q / 49, ri = q - lzi * 49, lhi = ri / 7, lwi = ri - lhi * 7;
      int lzj = kv / 49, rj = kv - lzj * 49, lhj = rj / 7, lwj = rj - lhj * 7;
      int idx = (lzi - lzj + 6) * 169 + (lhi - lhj + 6) * 13 + (lwi - lwj + 6);
      val = rel[idx * 4 + h];
    }
    biasH[gid] = (_Float16)val;
    return;
  }
  int i = gid - 495616;
  if (i < 65536) {
    int n = i >> 7, k = i & 127;
    w1h[i] = (_Float16)w1[k * 512 + n];
  } else if (i < 131072) {
    int j = i - 65536; int n = j >> 9, k = j & 511;
    w2h[j] = (_Float16)w2[k * 128 + n];
  } else if (i < 180224) {
    int j = i - 131072; int n = j >> 7, k = j & 127;
    wqh[j] = (_Float16)wq[k * 384 + n];
  } else if (i < 196608) {
    int j = i - 180224; int n = j >> 7, k = j & 127;
    wph[j] = (_Float16)wp[k * 128 + n];
  }
}

// ---------------- LN1 + shift-gather + QKV GEMM ------------------------------
// One wave per 32-row pair (11 pairs/window); weights staged per block in LDS.
// Operand-swapped MFMA: D[col=quad*4+reg][token=ml] -> half4 global stores.
__global__ __launch_bounds__(256) void k_ln_qkv(
    const float* __restrict__ x, const float* __restrict__ g1,
    const float* __restrict__ b1, const _Float16* __restrict__ wqh,
    const float* __restrict__ bq, _Float16* __restrict__ qkv) {
  __shared__ __align__(16) _Float16 wb[128 * 136];  // 34,816 B
  const int tid = threadIdx.x, lane = tid & 63, wid = tid >> 6;
  const int ml = lane & 15, quad = lane >> 4;
  const int task = blockIdx.x * 4 + wid;  // 0..2815
  const int w = task / 11, pr = task - (task / 11) * 11;
  const int b_ = w >> 7, r = w & 127;
  const int wz = r >> 6, wh = (r >> 3) & 7, ww = r & 7;

  half8 a0[4], a1[4];
#pragma unroll
  for (int hf = 0; hf < 2; ++hf) {
    int t = pr * 32 + hf * 16 + ml; if (t > 342) t = 342;
    int lz = t / 49, rr = t - lz * 49, lh = rr / 7, lw = rr - lh * 7;
    int oz = wz * 7 + lz + 3; if (oz >= 14) oz -= 14;
    int oh = wh * 7 + lh + 3; if (oh >= 56) oh -= 56;
    int ow = ww * 7 + lw + 3; if (ow >= 56) ow -= 56;
    const float* xp = x + ((((b_ * 14 + oz) * 56 + oh) * 56 + ow) << 7);
    float xv[32];
    float s = 0.f, ss = 0.f;
#pragma unroll
    for (int ks = 0; ks < 4; ++ks) {
      float4 p0 = *(const float4*)(xp + ks * 32 + quad * 8);
      float4 p1 = *(const float4*)(xp + ks * 32 + quad * 8 + 4);
      xv[ks * 8 + 0] = p0.x; xv[ks * 8 + 1] = p0.y; xv[ks * 8 + 2] = p0.z; xv[ks * 8 + 3] = p0.w;
      xv[ks * 8 + 4] = p1.x; xv[ks * 8 + 5] = p1.y; xv[ks * 8 + 6] = p1.z; xv[ks * 8 + 7] = p1.w;
      s += (p0.x + p0.y) + (p0.z + p0.w) + (p1.x + p1.y) + (p1.z + p1.w);
      ss += (p0.x * p0.x + p0.y * p0.y) + (p0.z * p0.z + p0.w * p0.w) +
            (p1.x * p1.x + p1.y * p1.y) + (p1.z * p1.z + p1.w * p1.w);
    }
    s += __shfl_xor(s, 16); s += __shfl_xor(s, 32);
    ss += __shfl_xor(ss, 16); ss += __shfl_xor(ss, 32);
    float mean = s * 0.0078125f;
    float rstd = rsqrtf(ss * 0.0078125f - mean * mean + 1e-5f);
#pragma unroll
    for (int ks = 0; ks < 4; ++ks) {
      int k0 = ks * 32 + quad * 8;
      float4 gg0 = *(const float4*)(g1 + k0), gg1 = *(const float4*)(g1 + k0 + 4);
      float4 bb0 = *(const float4*)(b1 + k0), bb1 = *(const float4*)(b1 + k0 + 4);
      half8 a;
      a[0] = (_Float16)((xv[ks * 8 + 0] - mean) * rstd * gg0.x + bb0.x);
      a[1] = (_Float16)((xv[ks * 8 + 1] - mean) * rstd * gg0.y + bb0.y);
      a[2] = (_Float16)((xv[ks * 8 + 2] - mean) * rstd * gg0.z + bb0.z);
      a[3] = (_Float16)((xv[ks * 8 + 3] - mean) * rstd * gg0.w + bb0.w);
      a[4] = (_Float16)((xv[ks * 8 + 4] - mean) * rstd * gg1.x + bb1.x);
      a[5] = (_Float16)((xv[ks * 8 + 5] - mean) * rstd * gg1.y + bb1.y);
      a[6] = (_Float16)((xv[ks * 8 + 6] - mean) * rstd * gg1.z + bb1.z);
      a[7] = (_Float16)((xv[ks * 8 + 7] - mean) * rstd * gg1.w + bb1.w);
      if (hf == 0) a0[ks] = a; else a1[ks] = a;
    }
  }

  const int t0 = pr * 32 + ml;        // always < 343 (pr<=10 -> max 335)
  const int t1 = t0 + 16;             // may exceed 342 -> guarded
  _Float16* q0 = qkv + ((size_t)w * 343 + t0) * 384;
  _Float16* q1 = qkv + ((size_t)w * 343 + (t1 < 343 ? t1 : 342)) * 384;

  for (int c = 0; c < 3; ++c) {  // 3 chunks of 128 qkv columns
    __syncthreads();
    stage_tile(wb, wqh + (size_t)c * 128 * 128, 128, tid);
    __syncthreads();
    for (int ntl = 0; ntl < 8; ++ntl) {
      floatx4 acc0 = {0.f, 0.f, 0.f, 0.f}, acc1 = {0.f, 0.f, 0.f, 0.f};
#pragma unroll
      for (int ks = 0; ks < 4; ++ks) {
        half8 bb = *(const half8*)&wb[(ntl * 16 + ml) * 136 + ks * 32 + quad * 8];
        acc0 = MFMA(bb, a0[ks], acc0);   // D[col=quad*4+reg][token=ml]
        acc1 = MFMA(bb, a1[ks], acc1);
      }
      const int colb = c * 128 + ntl * 16 + quad * 4;
      float qb[4]; f4arr(*(const float4*)&bq[colb], qb);
      half4 s0, s1;
#pragma unroll
      for (int reg = 0; reg < 4; ++reg) {
        s0[reg] = (_Float16)(acc0[reg] + qb[reg]);
        s1[reg] = (_Float16)(acc1[reg] + qb[reg]);
      }
      *(half4*)&q0[colb] = s0;
      if (t1 < 343) *(half4*)&q1[colb] = s1;
    }
  }
}

// ---------------- attention: one 512-thread block per (window, head) --------
// Swapped QK^T: S in D[kv=quad*4+reg][q=ml]. Grouped (8,8,6) phases: batch of
// independent bias+pen loads -> batch of independent QK MFMAs -> exp+PV.
// Mask is a precomputed LDS penalty table pen[rg][kv] (0 or -30000) folded
// into the bias with packed f16 adds. PV accumulates unnormalized; 1/sum at
// the end. exp(-29998..) == 0.0f for masked/pad lanes, as before.
__global__ __launch_bounds__(512, 2) void k_attn(const _Float16* __restrict__ qkv,
                                                 const _Float16* __restrict__ biasH,
                                                 _Float16* __restrict__ aout) {
  __shared__ __align__(16) _Float16 kl[352 * 40];    // 28,160 B  K[token][d]
  __shared__ __align__(16) _Float16 vt[32 * 364];    // 23,296 B  V^T[d][token]
  __shared__ __align__(16) _Float16 pen[27 * 360];   // 19,440 B  pen[rg][kv]
  __shared__ __align__(4) unsigned char region[352];
  const int tid = threadIdx.x;
  const int w = blockIdx.x >> 2, head = blockIdx.x & 3;
  const int r = w & 127;
  const int wz = r >> 6, wh = (r >> 3) & 7, ww = r & 7;
  const bool fz = (wz == 1), fh = (wh == 7), fw = (ww == 7);

  for (int t = tid; t < 352; t += 512) {
    int rg = 255;
    if (t < 343) {
      int lz = t / 49, rr = t - lz * 49, lh = rr / 7, lw = rr - lh * 7;
      int rz = fz ? (lz < 4 ? 1 : 2) : 0;
      int rh2 = fh ? (lh < 4 ? 1 : 2) : 0;
      int rw2 = fw ? (lw < 4 ? 1 : 2) : 0;
      rg = rz * 9 + rh2 * 3 + rw2;
    }
    region[t] = (unsigned char)rg;
  }
  // penalty table: pen[rg][t] = (region(t) == rg) ? 0 : -30000
  for (int e = tid; e < 27 * 352; e += 512) {
    int rg = e / 352, t = e - rg * 352;
    int rt_ = 255;
    if (t < 343) {
      int lz = t / 49, rr = t - lz * 49, lh = rr / 7, lw = rr - lh * 7;
      int rz = fz ? (lz < 4 ? 1 : 2) : 0;
      int rh2 = fh ? (lh < 4 ? 1 : 2) : 0;
      int rw2 = fw ? (lw < 4 ? 1 : 2) : 0;
      rt_ = rz * 9 + rh2 * 3 + rw2;
    }
    pen[rg * 360 + t] = (rt_ == rg) ? (_Float16)0.f : (_Float16)(-30000.f);
  }
  const _Float16* qkvw = qkv + (size_t)w * 343 * 384;
  for (int e = tid; e < 352 * 4; e += 512) {  // K staging, half8-vectorized
    int t = e >> 2, d8 = (e & 3) * 8;
    half8 v;
    if (t < 343) {
      v = *(const half8*)&qkvw[t * 384 + 128 + head * 32 + d8];
    } else {
#pragma unroll
      for (int j = 0; j < 8; ++j) v[j] = (_Float16)0.f;
    }
    *(half8*)&kl[t * 40 + d8] = v;
  }
  for (int e = tid; e < 343 * 4; e += 512) {  // V^T staging (half8 loads)
    int t = e >> 2, d8 = (e & 3) * 8;
    half8 v = *(const half8*)&qkvw[t * 384 + 256 + head * 32 + d8];
#pragma unroll
    for (int j = 0; j < 8; ++j) vt[(d8 + j) * 364 + t] = v[j];
  }
  for (int e = tid; e < 9 * 32; e += 512) {
    int t = 343 + (e >> 5), d = e & 31;
    vt[d * 364 + t] = (_Float16)0.f;
  }
  __syncthreads();  // the only barrier

  const int lane = tid & 63, wid = tid >> 6;
  const int ml = lane & 15, quad = lane >> 4;
  const float scale = 0.17677669529663687f;

  for (int rt = wid; rt < 22; rt += 8) {
    const int row0 = rt * 16;
    int qrow = row0 + ml; if (qrow > 342) qrow = 342;
    half8 bq8 = *(const half8*)&qkvw[qrow * 384 + head * 32 + quad * 8];
    const int rq = region[qrow];
    const _Float16* penr = &pen[rq * 360 + quad * 4];
    const _Float16* bb = &biasH[(size_t)((head * 22 + rt) * 22) * 256 + ml * 16 + quad * 4];

    floatx4 o0 = {0.f, 0.f, 0.f, 0.f}, o1 = {0.f, 0.f, 0.f, 0.f};
    floatx4 sm4 = {0.f, 0.f, 0.f, 0.f};
#pragma unroll
    for (int g = 0; g < 3; ++g) {       // groups of 8,8,6 kv-tiles
      const int G = (g < 2) ? 8 : 6;
      const int nb = g * 8;
      half4 bp[8];
      floatx4 S[8];
#pragma unroll
      for (int k = 0; k < 8; ++k) if (k < G) {   // batched bias+pen loads
        half4 b4 = *(const half4*)&bb[(nb + k) * 256];
        half4 p4 = *(const half4*)&penr[(nb + k) * 16];
        bp[k] = b4 + p4;                         // packed f16 adds
      }
#pragma unroll
      for (int k = 0; k < 8; ++k) if (k < G) {   // batched independent QK
        half8 ak = *(const half8*)&kl[((nb + k) * 16 + ml) * 40 + quad * 8];
        S[k] = MFMA(ak, bq8, (floatx4){0.f, 0.f, 0.f, 0.f});  // D[kv][q]
      }
#pragma unroll
      for (int k = 0; k < 8; ++k) if (k < G) {   // exp + PV accumulate
        half4 p;
#pragma unroll
        for (int reg = 0; reg < 4; ++reg) {
          float v = fmaf(S[k][reg], scale, (float)bp[k][reg]);
          float e = __expf(v);  // masked/pad -> exactly 0.0f
          sm4[reg] += e;
          p[reg] = (_Float16)e;
        }
        half4 va0 = *(const half4*)&vt[ml * 364 + (nb + k) * 16 + quad * 4];
        half4 va1 = *(const half4*)&vt[(16 + ml) * 364 + (nb + k) * 16 + quad * 4];
        o0 = MFMA16(va0, p, o0);   // unnormalized PV accumulate
        o1 = MFMA16(va1, p, o1);
      }
    }
    float sm = (sm4[0] + sm4[1]) + (sm4[2] + sm4[3]);
    sm += __shfl_xor(sm, 16);
    sm += __shfl_xor(sm, 32);   // full denominator for q=row0+ml in-lane

    const int orow = row0 + ml;
    if (orow < 343) {
      float inv = 1.f / sm;
      _Float16* op = aout + ((size_t)w * 343 + orow) * 128 + head * 32;
      half4 s0, s1;
#pragma unroll
      for (int reg = 0; reg < 4; ++reg) {
        s0[reg] = (_Float16)(o0[reg] * inv);
        s1[reg] = (_Float16)(o1[reg] * inv);
      }
      *(half4*)&op[quad * 4] = s0;
      *(half4*)&op[16 + quad * 4] = s1;
    }
  }
}

// -------- fused proj + residual + LN2 + MLP + residual -> out ---------------
// 256 threads / 4 waves; ONE 16-row half-tile per wave (task = window*22+tk,
// grid 1408). ZERO barriers: MFMA B-frags (weights) read directly from
// L2-resident global memory (16B contiguous per lane); LDS = per-wave hc
// scratch only (17.4 KB). x1 in registers (px[nt]).
__global__ __launch_bounds__(256, 2) void k_pm(
    const _Float16* __restrict__ aout, const _Float16* __restrict__ wph,
    const float* __restrict__ bp, const float* __restrict__ x,
    const float* __restrict__ g2, const float* __restrict__ nb2,
    const _Float16* __restrict__ w1h, const float* __restrict__ bfc1,
    const _Float16* __restrict__ w2h, const float* __restrict__ bfc2,
    float* __restrict__ out) {
  __shared__ __align__(16) _Float16 hc[4][16 * 136];  // 17,408 B total
  const int tid = threadIdx.x, lane = tid & 63, wid = tid >> 6;
  const int ml = lane & 15, quad = lane >> 4;
  const int task = blockIdx.x * 4 + wid;  // 0..5631
  const int w = task / 22, tk = task - (task / 22) * 22;
  const int b_ = w >> 7, r = w & 127;
  const int wz = r >> 6, wh = (r >> 3) & 7, ww = r & 7;
  const _Float16* ap = aout + (size_t)w * 343 * 128;
  _Float16* hw = &hc[wid][0];

  // A-frags (attention output rows, token index = ml; pad rows clamped)
  int ra = tk * 16 + ml; if (ra > 342) ra = 342;
  half8 a0[4];
#pragma unroll
  for (int ks = 0; ks < 4; ++ks)
    a0[ks] = *(const half8*)&ap[ra * 128 + ks * 32 + quad * 8];

  // shifted global token index for this wave's 16 rows (token = ml)
  int tok;
  {
    int t = tk * 16 + ml;
    if (t < 343) {
      int lz = t / 49, rr = t - lz * 49, lh = rr / 7, lw = rr - lh * 7;
      int oz = wz * 7 + lz + 3; if (oz >= 14) oz -= 14;
      int oh = wh * 7 + lh + 3; if (oh >= 56) oh -= 56;
      int ow = ww * 7 + lw + 3; if (ow >= 56) ow -= 56;
      tok = ((b_ * 14 + oz) * 56 + oh) * 56 + ow;
    } else {
      tok = -1;
    }
  }

  // proj GEMM + bias + residual -> x1 in registers (px[nt][reg]:
  // channel = nt*16+quad*4+reg, token = ml). Weights direct from L2.
  const _Float16* wpr = wph + (size_t)ml * 128 + quad * 8;  // row base (+nt*16*128)
  floatx4 px[8];
  for (int nt = 0; nt < 8; ++nt) {
    const _Float16* wr = wpr + (size_t)nt * 16 * 128;
    half8 b0 = *(const half8*)&wr[0];
    half8 b1 = *(const half8*)&wr[32];
    half8 b2 = *(const half8*)&wr[64];
    half8 b3 = *(const half8*)&wr[96];
    floatx4 acc = {0.f, 0.f, 0.f, 0.f};
    acc = MFMA(b0, a0[0], acc);
    acc = MFMA(b1, a0[1], acc);
    acc = MFMA(b2, a0[2], acc);
    acc = MFMA(b3, a0[3], acc);
    const int colb = nt * 16 + quad * 4;
    float pb4[4]; f4arr(*(const float4*)&bp[colb], pb4);
    float xr[4] = {0.f, 0.f, 0.f, 0.f};
    if (tok >= 0) f4arr(*(const float4*)&x[(size_t)tok * 128 + colb], xr);
#pragma unroll
    for (int reg = 0; reg < 4; ++reg)
      px[nt][reg] = acc[reg] + pb4[reg] + xr[reg];
  }

  // LN2 stats per token: in-lane sum over 32 channel regs + 2 quad shuffles
  float mean, rstd;
  {
    float s = 0.f, ss = 0.f;
#pragma unroll
    for (int nt = 0; nt < 8; ++nt)
#pragma unroll
      for (int reg = 0; reg < 4; ++reg) {
        float v = px[nt][reg];
        s += v; ss += v * v;
      }
    s += __shfl_xor(s, 16); s += __shfl_xor(s, 32);
    ss += __shfl_xor(ss, 16); ss += __shfl_xor(ss, 32);
    mean = s * 0.0078125f;
    rstd = rsqrtf(ss * 0.0078125f - mean * mean + 1e-5f);
  }

  // y = LN2(x1) -> hw tile via packed half4 stores, then A-frags
  // (per-wave buffer; in-wave LDS write->read ordering via lgkmcnt)
  for (int nt = 0; nt < 8; ++nt) {
    const int colb = nt * 16 + quad * 4;
    float g4[4], nb4[4];
    f4arr(*(const float4*)&g2[colb], g4);
    f4arr(*(const float4*)&nb2[colb], nb4);
    half4 h;
#pragma unroll
    for (int reg = 0; reg < 4; ++reg)
      h[reg] = (_Float16)((px[nt][reg] - mean) * rstd * g4[reg] + nb4[reg]);
    *(half4*)&hw[ml * 136 + colb] = h;
  }
  half8 ay[4];
#pragma unroll
  for (int ks = 0; ks < 4; ++ks)
    ay[ks] = *(const half8*)&hw[ml * 136 + ks * 32 + quad * 8];

  // fc1 + GELU -> hw chunk; fc2 partial accumulation (fused over 4 chunks).
  // All weight frags direct from L2; no barriers anywhere.
  floatx4 acc2[8];
#pragma unroll
  for (int nt = 0; nt < 8; ++nt) acc2[nt] = (floatx4){0.f, 0.f, 0.f, 0.f};

  const _Float16* w1r = w1h + (size_t)ml * 128 + quad * 8;   // + (ch*128+nt*16)*128
  const _Float16* w2r = w2h + (size_t)ml * 512 + quad * 8;   // + nt*16*512 + ch*128

  for (int ch = 0; ch < 4; ++ch) {
    // fc1: h[nmlp col = ch*128 + nt*16 + quad*4+reg][token = ml]
    for (int nt = 0; nt < 8; ++nt) {
      const _Float16* wr = w1r + (size_t)(ch * 128 + nt * 16) * 128;
      half8 b0 = *(const half8*)&wr[0];
      half8 b1 = *(const half8*)&wr[32];
      half8 b2 = *(const half8*)&wr[64];
      half8 b3 = *(const half8*)&wr[96];
      floatx4 f0 = {0.f, 0.f, 0.f, 0.f};
      f0 = MFMA(b0, ay[0], f0);
      f0 = MFMA(b1, ay[1], f0);
      f0 = MFMA(b2, ay[2], f0);
      f0 = MFMA(b3, ay[3], f0);
      const int colb = nt * 16 + quad * 4;
      float fb4[4]; f4arr(*(const float4*)&bfc1[ch * 128 + colb], fb4);
      half4 h0;
#pragma unroll
      for (int reg = 0; reg < 4; ++reg)
        h0[reg] = (_Float16)gelu_f(f0[reg] + fb4[reg]);
      *(half4*)&hw[ml * 136 + colb] = h0;
    }
    // fc2 partial: A = h (from per-wave scratch), B-frags from L2
#pragma unroll
    for (int ks = 0; ks < 4; ++ks) {
      half8 A0 = *(const half8*)&hw[ml * 136 + ks * 32 + quad * 8];
#pragma unroll
      for (int nt = 0; nt < 8; ++nt) {
        half8 bb = *(const half8*)&w2r[(size_t)nt * 16 * 512 + ch * 128 + ks * 32];
        acc2[nt] = MFMA(bb, A0, acc2[nt]);
      }
    }
  }

  // epilogue: out = x1 + fc2 + bias, float4 per nt to shifted positions
  if (tok >= 0) {
    for (int nt = 0; nt < 8; ++nt) {
      const int colb = nt * 16 + quad * 4;
      float fb4[4]; f4arr(*(const float4*)&bfc2[colb], fb4);
      float4 o;
      o.x = px[nt][0] + acc2[nt][0] + fb4[0];
      o.y = px[nt][1] + acc2[nt][1] + fb4[1];
      o.z = px[nt][2] + acc2[nt][2] + fb4[2];
      o.w = px[nt][3] + acc2[nt][3] + fb4[3];
      *(float4*)&out[(size_t)tok * 128 + colb] = o;
    }
  }
}

extern "C" void kernel_launch(void* const* d_in, const int* in_sizes, int n_in,
                              void* d_out, int out_size, void* d_ws, size_t ws_size,
                              hipStream_t stream) {
  (void)in_sizes; (void)n_in; (void)out_size; (void)ws_size;
  const float* x   = (const float*)d_in[0];
  const float* g1  = (const float*)d_in[1];
  const float* b1  = (const float*)d_in[2];
  const float* wq  = (const float*)d_in[3];
  const float* bq  = (const float*)d_in[4];
  const float* rel = (const float*)d_in[5];
  const float* wp  = (const float*)d_in[6];
  const float* bp  = (const float*)d_in[7];
  const float* g2  = (const float*)d_in[8];
  const float* b2_ = (const float*)d_in[9];
  const float* w1  = (const float*)d_in[10];
  const float* bf1 = (const float*)d_in[11];
  const float* w2  = (const float*)d_in[12];
  const float* bf2 = (const float*)d_in[13];

  char* ws = (char*)d_ws;
  _Float16* qkv   = (_Float16*)(ws);
  _Float16* aout  = (_Float16*)(ws + 67436544);
  _Float16* biasH = (_Float16*)(ws + 89915392);
  _Float16* w1h   = (_Float16*)(ws + 91897856);
  _Float16* w2h   = (_Float16*)(ws + 92028928);
  _Float16* wqh   = (_Float16*)(ws + 92160000);
  _Float16* wph   = (_Float16*)(ws + 92258304);
  float*    out   = (float*)d_out;

  hipLaunchKernelGGL(k_prep,   dim3(2704), dim3(256), 0, stream,
                     rel, biasH, w1, w2, wq, wp, w1h, w2h, wqh, wph);
  hipLaunchKernelGGL(k_ln_qkv, dim3(704),  dim3(256), 0, stream, x, g1, b1, wqh, bq, qkv);
  hipLaunchKernelGGL(k_attn,   dim3(1024), dim3(512), 0, stream, qkv, biasH, aout);
  hipLaunchKernelGGL(k_pm,     dim3(1408), dim3(256), 0, stream,
                     aout, wph, bp, x, g2, b2_, w1h, bf1, w2h, bf2, out);
}

// Round 22
// 281.499 us; speedup vs baseline: 1.4875x; 1.4875x over previous
//
#include <hip/hip_runtime.h>

// SwinTransformerBlock3D on MI355X (gfx950). fp32 in/out, f16 MFMA internals.
//
// FINAL verified configuration (280.2 us, rounds 8/14): k_pm with 32-row
// per-wave hc scratch, 69.6 KB LDS, launch_bounds(256,2) -> 128 VGPR, zero
// spill. Experiments refuted: LDS-shrink (spills: live set == 128 cap),
// 512-thread blocks (barrier cost > occupancy gain), 3 blocks/CU (neutral),
// zero-barrier L2-direct weights (2.7x worse: loses 44x LDS amplification).
//
// ws layout (bytes):
//   [0)           qkv   f16 [256][343][384]   67,436,544
//   [67,436,544)  aout  f16 [256][343][128]   22,478,848
//   [89,915,392)  biasH f16 [4][22(rt)][22(nt)][16(ml)][4(quad)][4(reg)] 991,232
//   [91,897,856)  w1h   f16 [512][128]           131,072
//   [92,028,928)  w2h   f16 [128][512]           131,072
//   [92,160,000)  wqh   f16 [384][128]            98,304
//   [92,258,304)  wph   f16 [128][128]            32,768
//   total 92,291,072      (x1 lives in registers inside k_pm)

typedef __attribute__((ext_vector_type(8))) _Float16 half8;
typedef __attribute__((ext_vector_type(4))) _Float16 half4;
typedef __attribute__((ext_vector_type(4))) float floatx4;

#define DEV static __device__ __forceinline__

DEV floatx4 MFMA(half8 a, half8 b, floatx4 c) {
  return __builtin_amdgcn_mfma_f32_16x16x32_f16(a, b, c, 0, 0, 0);
}
DEV floatx4 MFMA16(half4 a, half4 b, floatx4 c) {
  return __builtin_amdgcn_mfma_f32_16x16x16f16(a, b, c, 0, 0, 0);
}

DEV float gelu_f(float v) {  // sigmoid-form GELU (abs err <~0.01; margin 0.109)
  return v / (1.f + __expf(-1.702f * v));
}

DEV void f4arr(float4 v, float o[4]) {
  o[0] = v.x; o[1] = v.y; o[2] = v.z; o[3] = v.w;
}

// ---- weight tile pipeline: [128 rows x 128 halves] via registers -----------
DEV void stage_load(half8 pf[8], const _Float16* src, int rst, int tid) {
#pragma unroll
  for (int it = 0; it < 8; ++it) {
    int e = it * 256 + tid;
    int row = e >> 4, seg = e & 15;
    pf[it] = *(const half8*)&src[(size_t)row * rst + seg * 8];
  }
}
DEV void stage_store(_Float16* wb, const half8 pf[8], int tid) {
#pragma unroll
  for (int it = 0; it < 8; ++it) {
    int e = it * 256 + tid;
    int row = e >> 4, seg = e & 15;
    *(half8*)&wb[row * 136 + seg * 8] = pf[it];
  }
}
// one-shot (used by k_ln_qkv)
DEV void stage_tile(_Float16* wb, const _Float16* src, int rst, int tid) {
  half8 pf[8];
  stage_load(pf, src, rst, tid);
  stage_store(wb, pf, tid);
}

// ---- combined prep: rel-bias into swapped-S D-layout (f16) + weights -------
// biasH layout [h][rt][nt][ml][quad][reg] (nt innermost tile dim -> 512 B
// stride, foldable into immediate offsets in k_attn's group loop).
__global__ __launch_bounds__(256) void k_prep(
    const float* __restrict__ rel, _Float16* __restrict__ biasH,
    const float* __restrict__ w1, const float* __restrict__ w2,
    const float* __restrict__ wq, const float* __restrict__ wp,
    _Float16* __restrict__ w1h, _Float16* __restrict__ w2h,
    _Float16* __restrict__ wqh, _Float16* __restrict__ wph) {
  int gid = blockIdx.x * 256 + threadIdx.x;
  if (gid < 495616) {  // biasH[h][rt][nt][ml][quad][reg]; pads = -30000
    int reg = gid & 3, quad = (gid >> 2) & 3, ml = (gid >> 4) & 15;
    int u = gid >> 8;
    int nt = u % 22; u /= 22;
    int rt = u % 22; int h = u / 22;
    int q = rt * 16 + ml, kv = nt * 16 + quad * 4 + reg;
    float val = -30000.f;
    if (q < 343 && kv < 343) {
      int lzi = q / 49, ri = q - lzi * 49, lhi = ri / 7, lwi = ri - lhi * 7;
      int lzj = kv / 49, rj = kv - lzj * 49, lhj = rj / 7, lwj = rj - lhj * 7;
      int idx = (lzi - lzj + 6) * 169 + (lhi - lhj + 6) * 13 + (lwi - lwj + 6);
      val = rel[idx * 4 + h];
    }
    biasH[gid] = (_Float16)val;
    return;
  }
  int i = gid - 495616;
  if (i < 65536) {
    int n = i >> 7, k = i & 127;
    w1h[i] = (_Float16)w1[k * 512 + n];
  } else if (i < 131072) {
    int j = i - 65536; int n = j >> 9, k = j & 511;
    w2h[j] = (_Float16)w2[k * 128 + n];
  } else if (i < 180224) {
    int j = i - 131072; int n = j >> 7, k = j & 127;
    wqh[j] = (_Float16)wq[k * 384 + n];
  } else if (i < 196608) {
    int j = i - 180224; int n = j >> 7, k = j & 127;
    wph[j] = (_Float16)wp[k * 128 + n];
  }
}

// ---------------- LN1 + shift-gather + QKV GEMM ------------------------------
// One wave per 32-row pair (11 pairs/window); weights staged per block in LDS.
// Operand-swapped MFMA: D[col=quad*4+reg][token=ml] -> half4 global stores.
__global__ __launch_bounds__(256) void k_ln_qkv(
    const float* __restrict__ x, const float* __restrict__ g1,
    const float* __restrict__ b1, const _Float16* __restrict__ wqh,
    const float* __restrict__ bq, _Float16* __restrict__ qkv) {
  __shared__ __align__(16) _Float16 wb[128 * 136];  // 34,816 B
  const int tid = threadIdx.x, lane = tid & 63, wid = tid >> 6;
  const int ml = lane & 15, quad = lane >> 4;
  const int task = blockIdx.x * 4 + wid;  // 0..2815
  const int w = task / 11, pr = task - (task / 11) * 11;
  const int b_ = w >> 7, r = w & 127;
  const int wz = r >> 6, wh = (r >> 3) & 7, ww = r & 7;

  half8 a0[4], a1[4];
#pragma unroll
  for (int hf = 0; hf < 2; ++hf) {
    int t = pr * 32 + hf * 16 + ml; if (t > 342) t = 342;
    int lz = t / 49, rr = t - lz * 49, lh = rr / 7, lw = rr - lh * 7;
    int oz = wz * 7 + lz + 3; if (oz >= 14) oz -= 14;
    int oh = wh * 7 + lh + 3; if (oh >= 56) oh -= 56;
    int ow = ww * 7 + lw + 3; if (ow >= 56) ow -= 56;
    const float* xp = x + ((((b_ * 14 + oz) * 56 + oh) * 56 + ow) << 7);
    float xv[32];
    float s = 0.f, ss = 0.f;
#pragma unroll
    for (int ks = 0; ks < 4; ++ks) {
      float4 p0 = *(const float4*)(xp + ks * 32 + quad * 8);
      float4 p1 = *(const float4*)(xp + ks * 32 + quad * 8 + 4);
      xv[ks * 8 + 0] = p0.x; xv[ks * 8 + 1] = p0.y; xv[ks * 8 + 2] = p0.z; xv[ks * 8 + 3] = p0.w;
      xv[ks * 8 + 4] = p1.x; xv[ks * 8 + 5] = p1.y; xv[ks * 8 + 6] = p1.z; xv[ks * 8 + 7] = p1.w;
      s += (p0.x + p0.y) + (p0.z + p0.w) + (p1.x + p1.y) + (p1.z + p1.w);
      ss += (p0.x * p0.x + p0.y * p0.y) + (p0.z * p0.z + p0.w * p0.w) +
            (p1.x * p1.x + p1.y * p1.y) + (p1.z * p1.z + p1.w * p1.w);
    }
    s += __shfl_xor(s, 16); s += __shfl_xor(s, 32);
    ss += __shfl_xor(ss, 16); ss += __shfl_xor(ss, 32);
    float mean = s * 0.0078125f;
    float rstd = rsqrtf(ss * 0.0078125f - mean * mean + 1e-5f);
#pragma unroll
    for (int ks = 0; ks < 4; ++ks) {
      int k0 = ks * 32 + quad * 8;
      float4 gg0 = *(const float4*)(g1 + k0), gg1 = *(const float4*)(g1 + k0 + 4);
      float4 bb0 = *(const float4*)(b1 + k0), bb1 = *(const float4*)(b1 + k0 + 4);
      half8 a;
      a[0] = (_Float16)((xv[ks * 8 + 0] - mean) * rstd * gg0.x + bb0.x);
      a[1] = (_Float16)((xv[ks * 8 + 1] - mean) * rstd * gg0.y + bb0.y);
      a[2] = (_Float16)((xv[ks * 8 + 2] - mean) * rstd * gg0.z + bb0.z);
      a[3] = (_Float16)((xv[ks * 8 + 3] - mean) * rstd * gg0.w + bb0.w);
      a[4] = (_Float16)((xv[ks * 8 + 4] - mean) * rstd * gg1.x + bb1.x);
      a[5] = (_Float16)((xv[ks * 8 + 5] - mean) * rstd * gg1.y + bb1.y);
      a[6] = (_Float16)((xv[ks * 8 + 6] - mean) * rstd * gg1.z + bb1.z);
      a[7] = (_Float16)((xv[ks * 8 + 7] - mean) * rstd * gg1.w + bb1.w);
      if (hf == 0) a0[ks] = a; else a1[ks] = a;
    }
  }

  const int t0 = pr * 32 + ml;        // always < 343 (pr<=10 -> max 335)
  const int t1 = t0 + 16;             // may exceed 342 -> guarded
  _Float16* q0 = qkv + ((size_t)w * 343 + t0) * 384;
  _Float16* q1 = qkv + ((size_t)w * 343 + (t1 < 343 ? t1 : 342)) * 384;

  for (int c = 0; c < 3; ++c) {  // 3 chunks of 128 qkv columns
    __syncthreads();
    stage_tile(wb, wqh + (size_t)c * 128 * 128, 128, tid);
    __syncthreads();
    for (int ntl = 0; ntl < 8; ++ntl) {
      floatx4 acc0 = {0.f, 0.f, 0.f, 0.f}, acc1 = {0.f, 0.f, 0.f, 0.f};
#pragma unroll
      for (int ks = 0; ks < 4; ++ks) {
        half8 bb = *(const half8*)&wb[(ntl * 16 + ml) * 136 + ks * 32 + quad * 8];
        acc0 = MFMA(bb, a0[ks], acc0);   // D[col=quad*4+reg][token=ml]
        acc1 = MFMA(bb, a1[ks], acc1);
      }
      const int colb = c * 128 + ntl * 16 + quad * 4;
      float qb[4]; f4arr(*(const float4*)&bq[colb], qb);
      half4 s0, s1;
#pragma unroll
      for (int reg = 0; reg < 4; ++reg) {
        s0[reg] = (_Float16)(acc0[reg] + qb[reg]);
        s1[reg] = (_Float16)(acc1[reg] + qb[reg]);
      }
      *(half4*)&q0[colb] = s0;
      if (t1 < 343) *(half4*)&q1[colb] = s1;
    }
  }
}

// ---------------- attention: one 512-thread block per (window, head) --------
// Swapped QK^T: S in D[kv=quad*4+reg][q=ml]. Grouped (8,8,6) phases: batch of
// independent bias+pen loads -> batch of independent QK MFMAs -> exp+PV.
// Mask is a precomputed LDS penalty table pen[rg][kv] (0 or -30000) folded
// into the bias with packed f16 adds. PV accumulates unnormalized; 1/sum at
// the end. exp(-29998..) == 0.0f for masked/pad lanes, as before.
__global__ __launch_bounds__(512, 2) void k_attn(const _Float16* __restrict__ qkv,
                                                 const _Float16* __restrict__ biasH,
                                                 _Float16* __restrict__ aout) {
  __shared__ __align__(16) _Float16 kl[352 * 40];    // 28,160 B  K[token][d]
  __shared__ __align__(16) _Float16 vt[32 * 364];    // 23,296 B  V^T[d][token]
  __shared__ __align__(16) _Float16 pen[27 * 360];   // 19,440 B  pen[rg][kv]
  __shared__ __align__(4) unsigned char region[352];
  const int tid = threadIdx.x;
  const int w = blockIdx.x >> 2, head = blockIdx.x & 3;
  const int r = w & 127;
  const int wz = r >> 6, wh = (r >> 3) & 7, ww = r & 7;
  const bool fz = (wz == 1), fh = (wh == 7), fw = (ww == 7);

  for (int t = tid; t < 352; t += 512) {
    int rg = 255;
    if (t < 343) {
      int lz = t / 49, rr = t - lz * 49, lh = rr / 7, lw = rr - lh * 7;
      int rz = fz ? (lz < 4 ? 1 : 2) : 0;
      int rh2 = fh ? (lh < 4 ? 1 : 2) : 0;
      int rw2 = fw ? (lw < 4 ? 1 : 2) : 0;
      rg = rz * 9 + rh2 * 3 + rw2;
    }
    region[t] = (unsigned char)rg;
  }
  // penalty table: pen[rg][t] = (region(t) == rg) ? 0 : -30000
  for (int e = tid; e < 27 * 352; e += 512) {
    int rg = e / 352, t = e - rg * 352;
    int rt_ = 255;
    if (t < 343) {
      int lz = t / 49, rr = t - lz * 49, lh = rr / 7, lw = rr - lh * 7;
      int rz = fz ? (lz < 4 ? 1 : 2) : 0;
      int rh2 = fh ? (lh < 4 ? 1 : 2) : 0;
      int rw2 = fw ? (lw < 4 ? 1 : 2) : 0;
      rt_ = rz * 9 + rh2 * 3 + rw2;
    }
    pen[rg * 360 + t] = (rt_ == rg) ? (_Float16)0.f : (_Float16)(-30000.f);
  }
  const _Float16* qkvw = qkv + (size_t)w * 343 * 384;
  for (int e = tid; e < 352 * 4; e += 512) {  // K staging, half8-vectorized
    int t = e >> 2, d8 = (e & 3) * 8;
    half8 v;
    if (t < 343) {
      v = *(const half8*)&qkvw[t * 384 + 128 + head * 32 + d8];
    } else {
#pragma unroll
      for (int j = 0; j < 8; ++j) v[j] = (_Float16)0.f;
    }
    *(half8*)&kl[t * 40 + d8] = v;
  }
  for (int e = tid; e < 343 * 4; e += 512) {  // V^T staging (half8 loads)
    int t = e >> 2, d8 = (e & 3) * 8;
    half8 v = *(const half8*)&qkvw[t * 384 + 256 + head * 32 + d8];
#pragma unroll
    for (int j = 0; j < 8; ++j) vt[(d8 + j) * 364 + t] = v[j];
  }
  for (int e = tid; e < 9 * 32; e += 512) {
    int t = 343 + (e >> 5), d = e & 31;
    vt[d * 364 + t] = (_Float16)0.f;
  }
  __syncthreads();  // the only barrier

  const int lane = tid & 63, wid = tid >> 6;
  const int ml = lane & 15, quad = lane >> 4;
  const float scale = 0.17677669529663687f;

  for (int rt = wid; rt < 22; rt += 8) {
    const int row0 = rt * 16;
    int qrow = row0 + ml; if (qrow > 342) qrow = 342;
    half8 bq8 = *(const half8*)&qkvw[qrow * 384 + head * 32 + quad * 8];
    const int rq = region[qrow];
    const _Float16* penr = &pen[rq * 360 + quad * 4];
    const _Float16* bb = &biasH[(size_t)((head * 22 + rt) * 22) * 256 + ml * 16 + quad * 4];

    floatx4 o0 = {0.f, 0.f, 0.f, 0.f}, o1 = {0.f, 0.f, 0.f, 0.f};
    floatx4 sm4 = {0.f, 0.f, 0.f, 0.f};
#pragma unroll
    for (int g = 0; g < 3; ++g) {       // groups of 8,8,6 kv-tiles
      const int G = (g < 2) ? 8 : 6;
      const int nb = g * 8;
      half4 bp[8];
      floatx4 S[8];
#pragma unroll
      for (int k = 0; k < 8; ++k) if (k < G) {   // batched bias+pen loads
        half4 b4 = *(const half4*)&bb[(nb + k) * 256];
        half4 p4 = *(const half4*)&penr[(nb + k) * 16];
        bp[k] = b4 + p4;                         // packed f16 adds
      }
#pragma unroll
      for (int k = 0; k < 8; ++k) if (k < G) {   // batched independent QK
        half8 ak = *(const half8*)&kl[((nb + k) * 16 + ml) * 40 + quad * 8];
        S[k] = MFMA(ak, bq8, (floatx4){0.f, 0.f, 0.f, 0.f});  // D[kv][q]
      }
#pragma unroll
      for (int k = 0; k < 8; ++k) if (k < G) {   // exp + PV accumulate
        half4 p;
#pragma unroll
        for (int reg = 0; reg < 4; ++reg) {
          float v = fmaf(S[k][reg], scale, (float)bp[k][reg]);
          float e = __expf(v);  // masked/pad -> exactly 0.0f
          sm4[reg] += e;
          p[reg] = (_Float16)e;
        }
        half4 va0 = *(const half4*)&vt[ml * 364 + (nb + k) * 16 + quad * 4];
        half4 va1 = *(const half4*)&vt[(16 + ml) * 364 + (nb + k) * 16 + quad * 4];
        o0 = MFMA16(va0, p, o0);   // unnormalized PV accumulate
        o1 = MFMA16(va1, p, o1);
      }
    }
    float sm = (sm4[0] + sm4[1]) + (sm4[2] + sm4[3]);
    sm += __shfl_xor(sm, 16);
    sm += __shfl_xor(sm, 32);   // full denominator for q=row0+ml in-lane

    const int orow = row0 + ml;
    if (orow < 343) {
      float inv = 1.f / sm;
      _Float16* op = aout + ((size_t)w * 343 + orow) * 128 + head * 32;
      half4 s0, s1;
#pragma unroll
      for (int reg = 0; reg < 4; ++reg) {
        s0[reg] = (_Float16)(o0[reg] * inv);
        s1[reg] = (_Float16)(o1[reg] * inv);
      }
      *(half4*)&op[quad * 4] = s0;
      *(half4*)&op[16 + quad * 4] = s1;
    }
  }
}

// -------- fused proj + residual + LN2 + MLP + residual -> out ---------------
// One wave per 32 window-rows; x1 in registers. Round-8 verified structure:
// 32-row per-wave hc scratch (69.6 KB LDS, 2 blocks/CU), zero spill at the
// 128-VGPR cap from launch_bounds(256,2).
__global__ __launch_bounds__(256, 2) void k_pm(
    const _Float16* __restrict__ aout, const _Float16* __restrict__ wph,
    const float* __restrict__ bp, const float* __restrict__ x,
    const float* __restrict__ g2, const float* __restrict__ nb2,
    const _Float16* __restrict__ w1h, const float* __restrict__ bfc1,
    const _Float16* __restrict__ w2h, const float* __restrict__ bfc2,
    float* __restrict__ out) {
  __shared__ __align__(16) _Float16 hc[4][32 * 136];  // 34,816 B
  __shared__ __align__(16) _Float16 wb[128 * 136];    // 34,816 B  (69.6 KB total)
  const int tid = threadIdx.x, lane = tid & 63, wid = tid >> 6;
  const int ml = lane & 15, quad = lane >> 4;
  const int task = blockIdx.x * 4 + wid;  // 0..2815
  const int w = task / 11, pr = task - (task / 11) * 11;
  const int b_ = w >> 7, r = w & 127;
  const int wz = r >> 6, wh = (r >> 3) & 7, ww = r & 7;
  const _Float16* ap = aout + (size_t)w * 343 * 128;
  _Float16* hw = &hc[wid][0];

  half8 pf[8];
  stage_load(pf, wph, 128, tid);  // prefetch proj weights

  // A-frags (attention output rows, token index = ml; pad rows clamped)
  int ra = pr * 32 + ml; if (ra > 342) ra = 342;
  int rbm = pr * 32 + 16 + ml; if (rbm > 342) rbm = 342;
  half8 a0[4], a1[4];
#pragma unroll
  for (int ks = 0; ks < 4; ++ks) {
    a0[ks] = *(const half8*)&ap[ra * 128 + ks * 32 + quad * 8];
    a1[ks] = *(const half8*)&ap[rbm * 128 + ks * 32 + quad * 8];
  }
  // shifted global token index: one per mt (token = ml within the half-tile)
  int tok[2];
#pragma unroll
  for (int mt = 0; mt < 2; ++mt) {
    int t = pr * 32 + mt * 16 + ml;
    if (t < 343) {
      int lz = t / 49, rr = t - lz * 49, lh = rr / 7, lw = rr - lh * 7;
      int oz = wz * 7 + lz + 3; if (oz >= 14) oz -= 14;
      int oh = wh * 7 + lh + 3; if (oh >= 56) oh -= 56;
      int ow = ww * 7 + lw + 3; if (ow >= 56) ow -= 56;
      tok[mt] = ((b_ * 14 + oz) * 56 + oh) * 56 + ow;
    } else {
      tok[mt] = -1;
    }
  }
  stage_store(wb, pf, tid);
  __syncthreads();  // wb(proj) ready
  stage_load(pf, w1h, 128, tid);  // prefetch w1 chunk 0 (overlaps proj+LN2)

  // proj GEMM + bias + residual -> x1 in registers (px[nt][mt][reg]:
  // channel = nt*16+quad*4+reg, token = mt*16+ml)
  floatx4 px[8][2];
  for (int nt = 0; nt < 8; ++nt) {
    floatx4 acc0 = {0.f, 0.f, 0.f, 0.f}, acc1 = {0.f, 0.f, 0.f, 0.f};
#pragma unroll
    for (int ks = 0; ks < 4; ++ks) {
      half8 bb = *(const half8*)&wb[(nt * 16 + ml) * 136 + ks * 32 + quad * 8];
      acc0 = MFMA(bb, a0[ks], acc0);
      acc1 = MFMA(bb, a1[ks], acc1);
    }
    const int colb = nt * 16 + quad * 4;
    float pb4[4]; f4arr(*(const float4*)&bp[colb], pb4);
    float xr0[4] = {0.f, 0.f, 0.f, 0.f}, xr1[4] = {0.f, 0.f, 0.f, 0.f};
    if (tok[0] >= 0) f4arr(*(const float4*)&x[(size_t)tok[0] * 128 + colb], xr0);
    if (tok[1] >= 0) f4arr(*(const float4*)&x[(size_t)tok[1] * 128 + colb], xr1);
#pragma unroll
    for (int reg = 0; reg < 4; ++reg) {
      px[nt][0][reg] = acc0[reg] + pb4[reg] + xr0[reg];
      px[nt][1][reg] = acc1[reg] + pb4[reg] + xr1[reg];
    }
  }

  // LN2 stats per token: in-lane sum over 32 channel regs + 2 quad shuffles
  float mean[2], rstd[2];
#pragma unroll
  for (int mt = 0; mt < 2; ++mt) {
    float s = 0.f, ss = 0.f;
#pragma unroll
    for (int nt = 0; nt < 8; ++nt)
#pragma unroll
      for (int reg = 0; reg < 4; ++reg) {
        float v = px[nt][mt][reg];
        s += v; ss += v * v;
      }
    s += __shfl_xor(s, 16); s += __shfl_xor(s, 32);
    ss += __shfl_xor(ss, 16); ss += __shfl_xor(ss, 32);
    float m = s * 0.0078125f;
    mean[mt] = m;
    rstd[mt] = rsqrtf(ss * 0.0078125f - m * m + 1e-5f);
  }

  // y = LN2(x1) -> hw tile via packed half4 stores, then A-frags
  for (int nt = 0; nt < 8; ++nt) {
    const int colb = nt * 16 + quad * 4;
    float g4[4], nb4[4];
    f4arr(*(const float4*)&g2[colb], g4);
    f4arr(*(const float4*)&nb2[colb], nb4);
#pragma unroll
    for (int mt = 0; mt < 2; ++mt) {
      half4 h;
#pragma unroll
      for (int reg = 0; reg < 4; ++reg)
        h[reg] = (_Float16)((px[nt][mt][reg] - mean[mt]) * rstd[mt] * g4[reg] + nb4[reg]);
      *(half4*)&hw[(mt * 16 + ml) * 136 + colb] = h;
    }
  }
  half8 ay[2][4];
#pragma unroll
  for (int mt = 0; mt < 2; ++mt)
#pragma unroll
    for (int ks = 0; ks < 4; ++ks)
      ay[mt][ks] = *(const half8*)&hw[(mt * 16 + ml) * 136 + ks * 32 + quad * 8];

  // fc1 + GELU -> hw chunk; fc2 partial accumulation (fused over 4 chunks)
  floatx4 acc2[8][2];
#pragma unroll
  for (int nt = 0; nt < 8; ++nt)
#pragma unroll
    for (int mt = 0; mt < 2; ++mt) acc2[nt][mt] = (floatx4){0.f, 0.f, 0.f, 0.f};

  for (int ch = 0; ch < 4; ++ch) {
    __syncthreads();               // previous wb consumers done
    stage_store(wb, pf, tid);      // w1[ch]
    __syncthreads();
    stage_load(pf, w2h + (size_t)ch * 128, 512, tid);  // prefetch w2[ch]
    for (int nt = 0; nt < 8; ++nt) {
      floatx4 f0 = {0.f, 0.f, 0.f, 0.f}, f1 = {0.f, 0.f, 0.f, 0.f};
#pragma unroll
      for (int ks = 0; ks < 4; ++ks) {
        half8 bb = *(const half8*)&wb[(nt * 16 + ml) * 136 + ks * 32 + quad * 8];
        f0 = MFMA(bb, ay[0][ks], f0);   // D[nmlp col=quad*4+reg][token=ml]
        f1 = MFMA(bb, ay[1][ks], f1);
      }
      const int colb = nt * 16 + quad * 4;
      float fb4[4]; f4arr(*(const float4*)&bfc1[ch * 128 + colb], fb4);
      half4 h0, h1;
#pragma unroll
      for (int reg = 0; reg < 4; ++reg) {
        h0[reg] = (_Float16)gelu_f(f0[reg] + fb4[reg]);
        h1[reg] = (_Float16)gelu_f(f1[reg] + fb4[reg]);
      }
      *(half4*)&hw[ml * 136 + colb] = h0;
      *(half4*)&hw[(16 + ml) * 136 + colb] = h1;
    }
    __syncthreads();               // fc1 consumers of wb done
    stage_store(wb, pf, tid);      // w2[ch]
    __syncthreads();
    if (ch < 3) stage_load(pf, w1h + (size_t)(ch + 1) * 128 * 128, 128, tid);
#pragma unroll
    for (int ks = 0; ks < 4; ++ks) {
      half8 A0 = *(const half8*)&hw[ml * 136 + ks * 32 + quad * 8];
      half8 A1 = *(const half8*)&hw[(16 + ml) * 136 + ks * 32 + quad * 8];
#pragma unroll
      for (int nt = 0; nt < 8; ++nt) {
        half8 bb = *(const half8*)&wb[(nt * 16 + ml) * 136 + ks * 32 + quad * 8];
        acc2[nt][0] = MFMA(bb, A0, acc2[nt][0]);
        acc2[nt][1] = MFMA(bb, A1, acc2[nt][1]);
      }
    }
  }

  // epilogue: out = x1 + fc2 + bias, float4 per (nt, mt) to shifted positions
  for (int nt = 0; nt < 8; ++nt) {
    const int colb = nt * 16 + quad * 4;
    float fb4[4]; f4arr(*(const float4*)&bfc2[colb], fb4);
#pragma unroll
    for (int mt = 0; mt < 2; ++mt) {
      if (tok[mt] >= 0) {
        float4 o;
        o.x = px[nt][mt][0] + acc2[nt][mt][0] + fb4[0];
        o.y = px[nt][mt][1] + acc2[nt][mt][1] + fb4[1];
        o.z = px[nt][mt][2] + acc2[nt][mt][2] + fb4[2];
        o.w = px[nt][mt][3] + acc2[nt][mt][3] + fb4[3];
        *(float4*)&out[(size_t)tok[mt] * 128 + colb] = o;
      }
    }
  }
}

extern "C" void kernel_launch(void* const* d_in, const int* in_sizes, int n_in,
                              void* d_out, int out_size, void* d_ws, size_t ws_size,
                              hipStream_t stream) {
  (void)in_sizes; (void)n_in; (void)out_size; (void)ws_size;
  const float* x   = (const float*)d_in[0];
  const float* g1  = (const float*)d_in[1];
  const float* b1  = (const float*)d_in[2];
  const float* wq  = (const float*)d_in[3];
  const float* bq  = (const float*)d_in[4];
  const float* rel = (const float*)d_in[5];
  const float* wp  = (const float*)d_in[6];
  const float* bp  = (const float*)d_in[7];
  const float* g2  = (const float*)d_in[8];
  const float* b2_ = (const float*)d_in[9];
  const float* w1  = (const float*)d_in[10];
  const float* bf1 = (const float*)d_in[11];
  const float* w2  = (const float*)d_in[12];
  const float* bf2 = (const float*)d_in[13];

  char* ws = (char*)d_ws;
  _Float16* qkv   = (_Float16*)(ws);
  _Float16* aout  = (_Float16*)(ws + 67436544);
  _Float16* biasH = (_Float16*)(ws + 89915392);
  _Float16* w1h   = (_Float16*)(ws + 91897856);
  _Float16* w2h   = (_Float16*)(ws + 92028928);
  _Float16* wqh   = (_Float16*)(ws + 92160000);
  _Float16* wph   = (_Float16*)(ws + 92258304);
  float*    out   = (float*)d_out;

  hipLaunchKernelGGL(k_prep,   dim3(2704), dim3(256), 0, stream,
                     rel, biasH, w1, w2, wq, wp, w1h, w2h, wqh, wph);
  hipLaunchKernelGGL(k_ln_qkv, dim3(704),  dim3(256), 0, stream, x, g1, b1, wqh, bq, qkv);
  hipLaunchKernelGGL(k_attn,   dim3(1024), dim3(512), 0, stream, qkv, biasH, aout);
  hipLaunchKernelGGL(k_pm,     dim3(704),  dim3(256), 0, stream,
                     aout, wph, bp, x, g2, b2_, w1h, bf1, w2h, bf2, out);
}

// Round 24
// 274.488 us; speedup vs baseline: 1.5255x; 1.0255x over previous
//
#include <hip/hip_runtime.h>

// SwinTransformerBlock3D on MI355X (gfx950). fp32 in/out, f16 MFMA internals.
//
// Verified base (280-281 us): k_pm round-8 structure (32-row hc, 69.6 KB LDS,
// (256,2) -> 128 VGPR, zero spill). This revision touches ONLY k_attn:
//  (a) prologue: one-pass region+pen table build (1 region calc per t, 27
//      strided pen writes) replacing 9.5K div+region computations per block;
//  (b) s_setprio(1) around the batched QK MFMA cluster (guide-measured +4-7%
//      on attention with independent waves).
//
// ws layout (bytes):
//   [0)           qkv   f16 [256][343][384]   67,436,544
//   [67,436,544)  aout  f16 [256][343][128]   22,478,848
//   [89,915,392)  biasH f16 [4][22(rt)][22(nt)][16(ml)][4(quad)][4(reg)] 991,232
//   [91,897,856)  w1h   f16 [512][128]           131,072
//   [92,028,928)  w2h   f16 [128][512]           131,072
//   [92,160,000)  wqh   f16 [384][128]            98,304
//   [92,258,304)  wph   f16 [128][128]            32,768
//   total 92,291,072      (x1 lives in registers inside k_pm)

typedef __attribute__((ext_vector_type(8))) _Float16 half8;
typedef __attribute__((ext_vector_type(4))) _Float16 half4;
typedef __attribute__((ext_vector_type(4))) float floatx4;

#define DEV static __device__ __forceinline__

DEV floatx4 MFMA(half8 a, half8 b, floatx4 c) {
  return __builtin_amdgcn_mfma_f32_16x16x32_f16(a, b, c, 0, 0, 0);
}
DEV floatx4 MFMA16(half4 a, half4 b, floatx4 c) {
  return __builtin_amdgcn_mfma_f32_16x16x16f16(a, b, c, 0, 0, 0);
}

DEV float gelu_f(float v) {  // sigmoid-form GELU (abs err <~0.01; margin 0.109)
  return v / (1.f + __expf(-1.702f * v));
}

DEV void f4arr(float4 v, float o[4]) {
  o[0] = v.x; o[1] = v.y; o[2] = v.z; o[3] = v.w;
}

// ---- weight tile pipeline: [128 rows x 128 halves] via registers -----------
DEV void stage_load(half8 pf[8], const _Float16* src, int rst, int tid) {
#pragma unroll
  for (int it = 0; it < 8; ++it) {
    int e = it * 256 + tid;
    int row = e >> 4, seg = e & 15;
    pf[it] = *(const half8*)&src[(size_t)row * rst + seg * 8];
  }
}
DEV void stage_store(_Float16* wb, const half8 pf[8], int tid) {
#pragma unroll
  for (int it = 0; it < 8; ++it) {
    int e = it * 256 + tid;
    int row = e >> 4, seg = e & 15;
    *(half8*)&wb[row * 136 + seg * 8] = pf[it];
  }
}
// one-shot (used by k_ln_qkv)
DEV void stage_tile(_Float16* wb, const _Float16* src, int rst, int tid) {
  half8 pf[8];
  stage_load(pf, src, rst, tid);
  stage_store(wb, pf, tid);
}

// ---- combined prep: rel-bias into swapped-S D-layout (f16) + weights -------
// biasH layout [h][rt][nt][ml][quad][reg] (nt innermost tile dim -> 512 B
// stride, foldable into immediate offsets in k_attn's group loop).
__global__ __launch_bounds__(256) void k_prep(
    const float* __restrict__ rel, _Float16* __restrict__ biasH,
    const float* __restrict__ w1, const float* __restrict__ w2,
    const float* __restrict__ wq, const float* __restrict__ wp,
    _Float16* __restrict__ w1h, _Float16* __restrict__ w2h,
    _Float16* __restrict__ wqh, _Float16* __restrict__ wph) {
  int gid = blockIdx.x * 256 + threadIdx.x;
  if (gid < 495616) {  // biasH[h][rt][nt][ml][quad][reg]; pads = -30000
    int reg = gid & 3, quad = (gid >> 2) & 3, ml = (gid >> 4) & 15;
    int u = gid >> 8;
    int nt = u % 22; u /= 22;
    int rt = u % 22; int h = u / 22;
    int q = rt * 16 + ml, kv = nt * 16 + quad * 4 + reg;
    float val = -30000.f;
    if (q < 343 && kv < 343) {
      int lzi = q / 49, ri = q - lzi * 49, lhi = ri / 7, lwi = ri - lhi * 7;
      int lzj = kv / 49, rj = kv - lzj * 49, lhj = rj / 7, lwj = rj - lhj * 7;
      int idx = (lzi - lzj + 6) * 169 + (lhi - lhj + 6) * 13 + (lwi - lwj + 6);
      val = rel[idx * 4 + h];
    }
    biasH[gid] = (_Float16)val;
    return;
  }
  int i = gid - 495616;
  if (i < 65536) {
    int n = i >> 7, k = i & 127;
    w1h[i] = (_Float16)w1[k * 512 + n];
  } else if (i < 131072) {
    int j = i - 65536; int n = j >> 9, k = j & 511;
    w2h[j] = (_Float16)w2[k * 128 + n];
  } else if (i < 180224) {
    int j = i - 131072; int n = j >> 7, k = j & 127;
    wqh[j] = (_Float16)wq[k * 384 + n];
  } else if (i < 196608) {
    int j = i - 180224; int n = j >> 7, k = j & 127;
    wph[j] = (_Float16)wp[k * 128 + n];
  }
}

// ---------------- LN1 + shift-gather + QKV GEMM ------------------------------
// One wave per 32-row pair (11 pairs/window); weights staged per block in LDS.
// Operand-swapped MFMA: D[col=quad*4+reg][token=ml] -> half4 global stores.
__global__ __launch_bounds__(256) void k_ln_qkv(
    const float* __restrict__ x, const float* __restrict__ g1,
    const float* __restrict__ b1, const _Float16* __restrict__ wqh,
    const float* __restrict__ bq, _Float16* __restrict__ qkv) {
  __shared__ __align__(16) _Float16 wb[128 * 136];  // 34,816 B
  const int tid = threadIdx.x, lane = tid & 63, wid = tid >> 6;
  const int ml = lane & 15, quad = lane >> 4;
  const int task = blockIdx.x * 4 + wid;  // 0..2815
  const int w = task / 11, pr = task - (task / 11) * 11;
  const int b_ = w >> 7, r = w & 127;
  const int wz = r >> 6, wh = (r >> 3) & 7, ww = r & 7;

  half8 a0[4], a1[4];
#pragma unroll
  for (int hf = 0; hf < 2; ++hf) {
    int t = pr * 32 + hf * 16 + ml; if (t > 342) t = 342;
    int lz = t / 49, rr = t - lz * 49, lh = rr / 7, lw = rr - lh * 7;
    int oz = wz * 7 + lz + 3; if (oz >= 14) oz -= 14;
    int oh = wh * 7 + lh + 3; if (oh >= 56) oh -= 56;
    int ow = ww * 7 + lw + 3; if (ow >= 56) ow -= 56;
    const float* xp = x + ((((b_ * 14 + oz) * 56 + oh) * 56 + ow) << 7);
    float xv[32];
    float s = 0.f, ss = 0.f;
#pragma unroll
    for (int ks = 0; ks < 4; ++ks) {
      float4 p0 = *(const float4*)(xp + ks * 32 + quad * 8);
      float4 p1 = *(const float4*)(xp + ks * 32 + quad * 8 + 4);
      xv[ks * 8 + 0] = p0.x; xv[ks * 8 + 1] = p0.y; xv[ks * 8 + 2] = p0.z; xv[ks * 8 + 3] = p0.w;
      xv[ks * 8 + 4] = p1.x; xv[ks * 8 + 5] = p1.y; xv[ks * 8 + 6] = p1.z; xv[ks * 8 + 7] = p1.w;
      s += (p0.x + p0.y) + (p0.z + p0.w) + (p1.x + p1.y) + (p1.z + p1.w);
      ss += (p0.x * p0.x + p0.y * p0.y) + (p0.z * p0.z + p0.w * p0.w) +
            (p1.x * p1.x + p1.y * p1.y) + (p1.z * p1.z + p1.w * p1.w);
    }
    s += __shfl_xor(s, 16); s += __shfl_xor(s, 32);
    ss += __shfl_xor(ss, 16); ss += __shfl_xor(ss, 32);
    float mean = s * 0.0078125f;
    float rstd = rsqrtf(ss * 0.0078125f - mean * mean + 1e-5f);
#pragma unroll
    for (int ks = 0; ks < 4; ++ks) {
      int k0 = ks * 32 + quad * 8;
      float4 gg0 = *(const float4*)(g1 + k0), gg1 = *(const float4*)(g1 + k0 + 4);
      float4 bb0 = *(const float4*)(b1 + k0), bb1 = *(const float4*)(b1 + k0 + 4);
      half8 a;
      a[0] = (_Float16)((xv[ks * 8 + 0] - mean) * rstd * gg0.x + bb0.x);
      a[1] = (_Float16)((xv[ks * 8 + 1] - mean) * rstd * gg0.y + bb0.y);
      a[2] = (_Float16)((xv[ks * 8 + 2] - mean) * rstd * gg0.z + bb0.z);
      a[3] = (_Float16)((xv[ks * 8 + 3] - mean) * rstd * gg0.w + bb0.w);
      a[4] = (_Float16)((xv[ks * 8 + 4] - mean) * rstd * gg1.x + bb1.x);
      a[5] = (_Float16)((xv[ks * 8 + 5] - mean) * rstd * gg1.y + bb1.y);
      a[6] = (_Float16)((xv[ks * 8 + 6] - mean) * rstd * gg1.z + bb1.z);
      a[7] = (_Float16)((xv[ks * 8 + 7] - mean) * rstd * gg1.w + bb1.w);
      if (hf == 0) a0[ks] = a; else a1[ks] = a;
    }
  }

  const int t0 = pr * 32 + ml;        // always < 343 (pr<=10 -> max 335)
  const int t1 = t0 + 16;             // may exceed 342 -> guarded
  _Float16* q0 = qkv + ((size_t)w * 343 + t0) * 384;
  _Float16* q1 = qkv + ((size_t)w * 343 + (t1 < 343 ? t1 : 342)) * 384;

  for (int c = 0; c < 3; ++c) {  // 3 chunks of 128 qkv columns
    __syncthreads();
    stage_tile(wb, wqh + (size_t)c * 128 * 128, 128, tid);
    __syncthreads();
    for (int ntl = 0; ntl < 8; ++ntl) {
      floatx4 acc0 = {0.f, 0.f, 0.f, 0.f}, acc1 = {0.f, 0.f, 0.f, 0.f};
#pragma unroll
      for (int ks = 0; ks < 4; ++ks) {
        half8 bb = *(const half8*)&wb[(ntl * 16 + ml) * 136 + ks * 32 + quad * 8];
        acc0 = MFMA(bb, a0[ks], acc0);   // D[col=quad*4+reg][token=ml]
        acc1 = MFMA(bb, a1[ks], acc1);
      }
      const int colb = c * 128 + ntl * 16 + quad * 4;
      float qb[4]; f4arr(*(const float4*)&bq[colb], qb);
      half4 s0, s1;
#pragma unroll
      for (int reg = 0; reg < 4; ++reg) {
        s0[reg] = (_Float16)(acc0[reg] + qb[reg]);
        s1[reg] = (_Float16)(acc1[reg] + qb[reg]);
      }
      *(half4*)&q0[colb] = s0;
      if (t1 < 343) *(half4*)&q1[colb] = s1;
    }
  }
}

// ---------------- attention: one 512-thread block per (window, head) --------
// Swapped QK^T: S in D[kv=quad*4+reg][q=ml]. Grouped (8,8,6) phases. One-pass
// prologue builds region[] and pen[] with a single region calc per token.
// s_setprio(1) wraps the batched QK MFMA cluster (waves independent after the
// single barrier -> the guide-measured +4-7% attn regime).
__global__ __launch_bounds__(512, 2) void k_attn(const _Float16* __restrict__ qkv,
                                                 const _Float16* __restrict__ biasH,
                                                 _Float16* __restrict__ aout) {
  __shared__ __align__(16) _Float16 kl[352 * 40];    // 28,160 B  K[token][d]
  __shared__ __align__(16) _Float16 vt[32 * 364];    // 23,296 B  V^T[d][token]
  __shared__ __align__(16) _Float16 pen[27 * 360];   // 19,440 B  pen[rg][kv]
  __shared__ __align__(4) unsigned char region[352];
  const int tid = threadIdx.x;
  const int w = blockIdx.x >> 2, head = blockIdx.x & 3;
  const int r = w & 127;
  const int wz = r >> 6, wh = (r >> 3) & 7, ww = r & 7;
  const bool fz = (wz == 1), fh = (wh == 7), fw = (ww == 7);

  // one-pass region + penalty build: region calc ONCE per token t, then all
  // 27 pen rows for that t (identical values to the two-pass version)
  for (int t = tid; t < 352; t += 512) {
    int rt_ = 255;
    if (t < 343) {
      int lz = t / 49, rr = t - lz * 49, lh = rr / 7, lw = rr - lh * 7;
      int rz = fz ? (lz < 4 ? 1 : 2) : 0;
      int rh2 = fh ? (lh < 4 ? 1 : 2) : 0;
      int rw2 = fw ? (lw < 4 ? 1 : 2) : 0;
      rt_ = rz * 9 + rh2 * 3 + rw2;
    }
    region[t] = (unsigned char)rt_;
#pragma unroll
    for (int rg = 0; rg < 27; ++rg)
      pen[rg * 360 + t] = (rg == rt_) ? (_Float16)0.f : (_Float16)(-30000.f);
  }
  const _Float16* qkvw = qkv + (size_t)w * 343 * 384;
  for (int e = tid; e < 352 * 4; e += 512) {  // K staging, half8-vectorized
    int t = e >> 2, d8 = (e & 3) * 8;
    half8 v;
    if (t < 343) {
      v = *(const half8*)&qkvw[t * 384 + 128 + head * 32 + d8];
    } else {
#pragma unroll
      for (int j = 0; j < 8; ++j) v[j] = (_Float16)0.f;
    }
    *(half8*)&kl[t * 40 + d8] = v;
  }
  for (int e = tid; e < 343 * 4; e += 512) {  // V^T staging (half8 loads)
    int t = e >> 2, d8 = (e & 3) * 8;
    half8 v = *(const half8*)&qkvw[t * 384 + 256 + head * 32 + d8];
#pragma unroll
    for (int j = 0; j < 8; ++j) vt[(d8 + j) * 364 + t] = v[j];
  }
  for (int e = tid; e < 9 * 32; e += 512) {
    int t = 343 + (e >> 5), d = e & 31;
    vt[d * 364 + t] = (_Float16)0.f;
  }
  __syncthreads();  // the only barrier

  const int lane = tid & 63, wid = tid >> 6;
  const int ml = lane & 15, quad = lane >> 4;
  const float scale = 0.17677669529663687f;

  for (int rt = wid; rt < 22; rt += 8) {
    const int row0 = rt * 16;
    int qrow = row0 + ml; if (qrow > 342) qrow = 342;
    half8 bq8 = *(const half8*)&qkvw[qrow * 384 + head * 32 + quad * 8];
    const int rq = region[qrow];
    const _Float16* penr = &pen[rq * 360 + quad * 4];
    const _Float16* bb = &biasH[(size_t)((head * 22 + rt) * 22) * 256 + ml * 16 + quad * 4];

    floatx4 o0 = {0.f, 0.f, 0.f, 0.f}, o1 = {0.f, 0.f, 0.f, 0.f};
    floatx4 sm4 = {0.f, 0.f, 0.f, 0.f};
#pragma unroll
    for (int g = 0; g < 3; ++g) {       // groups of 8,8,6 kv-tiles
      const int G = (g < 2) ? 8 : 6;
      const int nb = g * 8;
      half4 bp[8];
      floatx4 S[8];
#pragma unroll
      for (int k = 0; k < 8; ++k) if (k < G) {   // batched bias+pen loads
        half4 b4 = *(const half4*)&bb[(nb + k) * 256];
        half4 p4 = *(const half4*)&penr[(nb + k) * 16];
        bp[k] = b4 + p4;                         // packed f16 adds
      }
      __builtin_amdgcn_s_setprio(1);
#pragma unroll
      for (int k = 0; k < 8; ++k) if (k < G) {   // batched independent QK
        half8 ak = *(const half8*)&kl[((nb + k) * 16 + ml) * 40 + quad * 8];
        S[k] = MFMA(ak, bq8, (floatx4){0.f, 0.f, 0.f, 0.f});  // D[kv][q]
      }
      __builtin_amdgcn_s_setprio(0);
#pragma unroll
      for (int k = 0; k < 8; ++k) if (k < G) {   // exp + PV accumulate
        half4 p;
#pragma unroll
        for (int reg = 0; reg < 4; ++reg) {
          float v = fmaf(S[k][reg], scale, (float)bp[k][reg]);
          float e = __expf(v);  // masked/pad -> exactly 0.0f
          sm4[reg] += e;
          p[reg] = (_Float16)e;
        }
        half4 va0 = *(const half4*)&vt[ml * 364 + (nb + k) * 16 + quad * 4];
        half4 va1 = *(const half4*)&vt[(16 + ml) * 364 + (nb + k) * 16 + quad * 4];
        o0 = MFMA16(va0, p, o0);   // unnormalized PV accumulate
        o1 = MFMA16(va1, p, o1);
      }
    }
    float sm = (sm4[0] + sm4[1]) + (sm4[2] + sm4[3]);
    sm += __shfl_xor(sm, 16);
    sm += __shfl_xor(sm, 32);   // full denominator for q=row0+ml in-lane

    const int orow = row0 + ml;
    if (orow < 343) {
      float inv = 1.f / sm;
      _Float16* op = aout + ((size_t)w * 343 + orow) * 128 + head * 32;
      half4 s0, s1;
#pragma unroll
      for (int reg = 0; reg < 4; ++reg) {
        s0[reg] = (_Float16)(o0[reg] * inv);
        s1[reg] = (_Float16)(o1[reg] * inv);
      }
      *(half4*)&op[quad * 4] = s0;
      *(half4*)&op[16 + quad * 4] = s1;
    }
  }
}

// -------- fused proj + residual + LN2 + MLP + residual -> out ---------------
// One wave per 32 window-rows; x1 in registers. Round-8 verified structure:
// 32-row per-wave hc scratch (69.6 KB LDS, 2 blocks/CU), zero spill at the
// 128-VGPR cap from launch_bounds(256,2).
__global__ __launch_bounds__(256, 2) void k_pm(
    const _Float16* __restrict__ aout, const _Float16* __restrict__ wph,
    const float* __restrict__ bp, const float* __restrict__ x,
    const float* __restrict__ g2, const float* __restrict__ nb2,
    const _Float16* __restrict__ w1h, const float* __restrict__ bfc1,
    const _Float16* __restrict__ w2h, const float* __restrict__ bfc2,
    float* __restrict__ out) {
  __shared__ __align__(16) _Float16 hc[4][32 * 136];  // 34,816 B
  __shared__ __align__(16) _Float16 wb[128 * 136];    // 34,816 B  (69.6 KB total)
  const int tid = threadIdx.x, lane = tid & 63, wid = tid >> 6;
  const int ml = lane & 15, quad = lane >> 4;
  const int task = blockIdx.x * 4 + wid;  // 0..2815
  const int w = task / 11, pr = task - (task / 11) * 11;
  const int b_ = w >> 7, r = w & 127;
  const int wz = r >> 6, wh = (r >> 3) & 7, ww = r & 7;
  const _Float16* ap = aout + (size_t)w * 343 * 128;
  _Float16* hw = &hc[wid][0];

  half8 pf[8];
  stage_load(pf, wph, 128, tid);  // prefetch proj weights

  // A-frags (attention output rows, token index = ml; pad rows clamped)
  int ra = pr * 32 + ml; if (ra > 342) ra = 342;
  int rbm = pr * 32 + 16 + ml; if (rbm > 342) rbm = 342;
  half8 a0[4], a1[4];
#pragma unroll
  for (int ks = 0; ks < 4; ++ks) {
    a0[ks] = *(const half8*)&ap[ra * 128 + ks * 32 + quad * 8];
    a1[ks] = *(const half8*)&ap[rbm * 128 + ks * 32 + quad * 8];
  }
  // shifted global token index: one per mt (token = ml within the half-tile)
  int tok[2];
#pragma unroll
  for (int mt = 0; mt < 2; ++mt) {
    int t = pr * 32 + mt * 16 + ml;
    if (t < 343) {
      int lz = t / 49, rr = t - lz * 49, lh = rr / 7, lw = rr - lh * 7;
      int oz = wz * 7 + lz + 3; if (oz >= 14) oz -= 14;
      int oh = wh * 7 + lh + 3; if (oh >= 56) oh -= 56;
      int ow = ww * 7 + lw + 3; if (ow >= 56) ow -= 56;
      tok[mt] = ((b_ * 14 + oz) * 56 + oh) * 56 + ow;
    } else {
      tok[mt] = -1;
    }
  }
  stage_store(wb, pf, tid);
  __syncthreads();  // wb(proj) ready
  stage_load(pf, w1h, 128, tid);  // prefetch w1 chunk 0 (overlaps proj+LN2)

  // proj GEMM + bias + residual -> x1 in registers (px[nt][mt][reg]:
  // channel = nt*16+quad*4+reg, token = mt*16+ml)
  floatx4 px[8][2];
  for (int nt = 0; nt < 8; ++nt) {
    floatx4 acc0 = {0.f, 0.f, 0.f, 0.f}, acc1 = {0.f, 0.f, 0.f, 0.f};
#pragma unroll
    for (int ks = 0; ks < 4; ++ks) {
      half8 bb = *(const half8*)&wb[(nt * 16 + ml) * 136 + ks * 32 + quad * 8];
      acc0 = MFMA(bb, a0[ks], acc0);
      acc1 = MFMA(bb, a1[ks], acc1);
    }
    const int colb = nt * 16 + quad * 4;
    float pb4[4]; f4arr(*(const float4*)&bp[colb], pb4);
    float xr0[4] = {0.f, 0.f, 0.f, 0.f}, xr1[4] = {0.f, 0.f, 0.f, 0.f};
    if (tok[0] >= 0) f4arr(*(const float4*)&x[(size_t)tok[0] * 128 + colb], xr0);
    if (tok[1] >= 0) f4arr(*(const float4*)&x[(size_t)tok[1] * 128 + colb], xr1);
#pragma unroll
    for (int reg = 0; reg < 4; ++reg) {
      px[nt][0][reg] = acc0[reg] + pb4[reg] + xr0[reg];
      px[nt][1][reg] = acc1[reg] + pb4[reg] + xr1[reg];
    }
  }

  // LN2 stats per token: in-lane sum over 32 channel regs + 2 quad shuffles
  float mean[2], rstd[2];
#pragma unroll
  for (int mt = 0; mt < 2; ++mt) {
    float s = 0.f, ss = 0.f;
#pragma unroll
    for (int nt = 0; nt < 8; ++nt)
#pragma unroll
      for (int reg = 0; reg < 4; ++reg) {
        float v = px[nt][mt][reg];
        s += v; ss += v * v;
      }
    s += __shfl_xor(s, 16); s += __shfl_xor(s, 32);
    ss += __shfl_xor(ss, 16); ss += __shfl_xor(ss, 32);
    float m = s * 0.0078125f;
    mean[mt] = m;
    rstd[mt] = rsqrtf(ss * 0.0078125f - m * m + 1e-5f);
  }

  // y = LN2(x1) -> hw tile via packed half4 stores, then A-frags
  for (int nt = 0; nt < 8; ++nt) {
    const int colb = nt * 16 + quad * 4;
    float g4[4], nb4[4];
    f4arr(*(const float4*)&g2[colb], g4);
    f4arr(*(const float4*)&nb2[colb], nb4);
#pragma unroll
    for (int mt = 0; mt < 2; ++mt) {
      half4 h;
#pragma unroll
      for (int reg = 0; reg < 4; ++reg)
        h[reg] = (_Float16)((px[nt][mt][reg] - mean[mt]) * rstd[mt] * g4[reg] + nb4[reg]);
      *(half4*)&hw[(mt * 16 + ml) * 136 + colb] = h;
    }
  }
  half8 ay[2][4];
#pragma unroll
  for (int mt = 0; mt < 2; ++mt)
#pragma unroll
    for (int ks = 0; ks < 4; ++ks)
      ay[mt][ks] = *(const half8*)&hw[(mt * 16 + ml) * 136 + ks * 32 + quad * 8];

  // fc1 + GELU -> hw chunk; fc2 partial accumulation (fused over 4 chunks)
  floatx4 acc2[8][2];
#pragma unroll
  for (int nt = 0; nt < 8; ++nt)
#pragma unroll
    for (int mt = 0; mt < 2; ++mt) acc2[nt][mt] = (floatx4){0.f, 0.f, 0.f, 0.f};

  for (int ch = 0; ch < 4; ++ch) {
    __syncthreads();               // previous wb consumers done
    stage_store(wb, pf, tid);      // w1[ch]
    __syncthreads();
    stage_load(pf, w2h + (size_t)ch * 128, 512, tid);  // prefetch w2[ch]
    for (int nt = 0; nt < 8; ++nt) {
      floatx4 f0 = {0.f, 0.f, 0.f, 0.f}, f1 = {0.f, 0.f, 0.f, 0.f};
#pragma unroll
      for (int ks = 0; ks < 4; ++ks) {
        half8 bb = *(const half8*)&wb[(nt * 16 + ml) * 136 + ks * 32 + quad * 8];
        f0 = MFMA(bb, ay[0][ks], f0);   // D[nmlp col=quad*4+reg][token=ml]
        f1 = MFMA(bb, ay[1][ks], f1);
      }
      const int colb = nt * 16 + quad * 4;
      float fb4[4]; f4arr(*(const float4*)&bfc1[ch * 128 + colb], fb4);
      half4 h0, h1;
#pragma unroll
      for (int reg = 0; reg < 4; ++reg) {
        h0[reg] = (_Float16)gelu_f(f0[reg] + fb4[reg]);
        h1[reg] = (_Float16)gelu_f(f1[reg] + fb4[reg]);
      }
      *(half4*)&hw[ml * 136 + colb] = h0;
      *(half4*)&hw[(16 + ml) * 136 + colb] = h1;
    }
    __syncthreads();               // fc1 consumers of wb done
    stage_store(wb, pf, tid);      // w2[ch]
    __syncthreads();
    if (ch < 3) stage_load(pf, w1h + (size_t)(ch + 1) * 128 * 128, 128, tid);
#pragma unroll
    for (int ks = 0; ks < 4; ++ks) {
      half8 A0 = *(const half8*)&hw[ml * 136 + ks * 32 + quad * 8];
      half8 A1 = *(const half8*)&hw[(16 + ml) * 136 + ks * 32 + quad * 8];
#pragma unroll
      for (int nt = 0; nt < 8; ++nt) {
        half8 bb = *(const half8*)&wb[(nt * 16 + ml) * 136 + ks * 32 + quad * 8];
        acc2[nt][0] = MFMA(bb, A0, acc2[nt][0]);
        acc2[nt][1] = MFMA(bb, A1, acc2[nt][1]);
      }
    }
  }

  // epilogue: out = x1 + fc2 + bias, float4 per (nt, mt) to shifted positions
  for (int nt = 0; nt < 8; ++nt) {
    const int colb = nt * 16 + quad * 4;
    float fb4[4]; f4arr(*(const float4*)&bfc2[colb], fb4);
#pragma unroll
    for (int mt = 0; mt < 2; ++mt) {
      if (tok[mt] >= 0) {
        float4 o;
        o.x = px[nt][mt][0] + acc2[nt][mt][0] + fb4[0];
        o.y = px[nt][mt][1] + acc2[nt][mt][1] + fb4[1];
        o.z = px[nt][mt][2] + acc2[nt][mt][2] + fb4[2];
        o.w = px[nt][mt][3] + acc2[nt][mt][3] + fb4[3];
        *(float4*)&out[(size_t)tok[mt] * 128 + colb] = o;
      }
    }
  }
}

extern "C" void kernel_launch(void* const* d_in, const int* in_sizes, int n_in,
                              void* d_out, int out_size, void* d_ws, size_t ws_size,
                              hipStream_t stream) {
  (void)in_sizes; (void)n_in; (void)out_size; (void)ws_size;
  const float* x   = (const float*)d_in[0];
  const float* g1  = (const float*)d_in[1];
  const float* b1  = (const float*)d_in[2];
  const float* wq  = (const float*)d_in[3];
  const float* bq  = (const float*)d_in[4];
  const float* rel = (const float*)d_in[5];
  const float* wp  = (const float*)d_in[6];
  const float* bp  = (const float*)d_in[7];
  const float* g2  = (const float*)d_in[8];
  const float* b2_ = (const float*)d_in[9];
  const float* w1  = (const float*)d_in[10];
  const float* bf1 = (const float*)d_in[11];
  const float* w2  = (const float*)d_in[12];
  const float* bf2 = (const float*)d_in[13];

  char* ws = (char*)d_ws;
  _Float16* qkv   = (_Float16*)(ws);
  _Float16* aout  = (_Float16*)(ws + 67436544);
  _Float16* biasH = (_Float16*)(ws + 89915392);
  _Float16* w1h   = (_Float16*)(ws + 91897856);
  _Float16* w2h   = (_Float16*)(ws + 92028928);
  _Float16* wqh   = (_Float16*)(ws + 92160000);
  _Float16* wph   = (_Float16*)(ws + 92258304);
  float*    out   = (float*)d_out;

  hipLaunchKernelGGL(k_prep,   dim3(2704), dim3(256), 0, stream,
                     rel, biasH, w1, w2, wq, wp, w1h, w2h, wqh, wph);
  hipLaunchKernelGGL(k_ln_qkv, dim3(704),  dim3(256), 0, stream, x, g1, b1, wqh, bq, qkv);
  hipLaunchKernelGGL(k_attn,   dim3(1024), dim3(512), 0, stream, qkv, biasH, aout);
  hipLaunchKernelGGL(k_pm,     dim3(704),  dim3(256), 0, stream,
                     aout, wph, bp, x, g2, b2_, w1h, bf1, w2h, bf2, out);
}